// Round 3
// baseline (838.299 us; speedup 1.0000x reference)
//
#include <hip/hip_runtime.h>
#include <float.h>
#include <math.h>

// Problem constants
#define D 256
#define NROWS 65536
#define RPB 64            // rows per block
#define EPS_GAP 5e-4f     // fp32 two-min gap below which we re-rank with np-mimic arithmetic

// ws float layout:
//  [0..3]     alpha (float, from fp64 softmax)
//  [4..963]   packed column norms ||c||^2 (packed col order: d0[0,64) d1[64,192) d2[192,448) d3[448,960))
//  [968..975] 4 doubles: per-dict loss accumulators (8B-aligned)
//  [976..983] 4 doubles: alpha in fp64
//  [1024..]   dicT[960][256] transposed dicts (packed row = packed col index)

// LDS x tile: [64 rows][256 dims], XOR-swizzled: phys = row*256 + (d ^ (row & 31)).
__device__ __forceinline__ int xs_idx(int row, int d) { return row * 256 + (d ^ (row & 31)); }

__global__ void vq_prep(const float* __restrict__ av,
                        const float* __restrict__ dc0, const float* __restrict__ dc1,
                        const float* __restrict__ dc2, const float* __restrict__ dc3,
                        float* __restrict__ ws)
{
    int t = blockIdx.x * 256 + threadIdx.x;
    if (t == 0) {
        double x0 = av[0], x1 = av[1], x2 = av[2], x3 = av[3];
        double m = fmax(fmax(x0, x1), fmax(x2, x3));
        double e0 = exp(x0 - m), e1 = exp(x1 - m), e2 = exp(x2 - m), e3 = exp(x3 - m);
        double inv = 1.0 / (e0 + e1 + e2 + e3);
        ws[0] = (float)(e0 * inv); ws[1] = (float)(e1 * inv);
        ws[2] = (float)(e2 * inv); ws[3] = (float)(e3 * inv);
        double* lacc = (double*)(ws + 968);
        lacc[0] = 0.0; lacc[1] = 0.0; lacc[2] = 0.0; lacc[3] = 0.0;   // re-zero every launch
        double* dal = (double*)(ws + 976);
        dal[0] = e0 * inv; dal[1] = e1 * inv; dal[2] = e2 * inv; dal[3] = e3 * inv;
    }
    if (t < 960) {
        const float* dic; int K, k;
        if      (t < 64)  { dic = dc0; K = 64;  k = t;       }
        else if (t < 192) { dic = dc1; K = 128; k = t - 64;  }
        else if (t < 448) { dic = dc2; K = 256; k = t - 192; }
        else              { dic = dc3; K = 512; k = t - 448; }
        float s = 0.0f;
        float* dT = ws + 1024 + (size_t)t * D;
        for (int d = 0; d < D; ++d) {
            float v = dic[d * K + k];
            s = fmaf(v, v, s);
            dT[d] = v;
        }
        ws[4 + t] = s;
    }
}

// One 64-column chunk of one dict. This wave covers local cols [lc0, lc0+16).
// Tracks two smallest (min1,idx1,min2) for the near-tie gap test.
template<int K>
__device__ __forceinline__ void chunk_min(
    const float* __restrict__ dic, int lc0,
    const float* __restrict__ xb, int xc,      // xb = xs + lane*256 ; xc = lane & 31
    const float* __restrict__ cnp,             // ws + 4 + gbase
    float& minv, int& mini, float& min2v, int gbase)
{
    float acc[16];
#pragma unroll
    for (int j = 0; j < 16; ++j) acc[j] = 0.0f;
    const float* bp = dic + lc0;
    float b0[16], b1[16];
#pragma unroll
    for (int j = 0; j < 16; ++j) b0[j] = bp[j];          // d = 0
    for (int d = 0; d < D; d += 2) {
        const float* p1 = bp + (size_t)(d + 1) * K;
#pragma unroll
        for (int j = 0; j < 16; ++j) b1[j] = p1[j];      // prefetch d+1
        float a0 = xb[d ^ xc];
#pragma unroll
        for (int j = 0; j < 16; ++j) acc[j] = fmaf(a0, b0[j], acc[j]);
        const float* p2 = bp + (size_t)((d + 2) & 255) * K;   // wraps at end (harmless reload)
#pragma unroll
        for (int j = 0; j < 16; ++j) b0[j] = p2[j];      // prefetch d+2
        float a1 = xb[(d + 1) ^ xc];
#pragma unroll
        for (int j = 0; j < 16; ++j) acc[j] = fmaf(a1, b1[j], acc[j]);
    }
#pragma unroll
    for (int j = 0; j < 16; ++j) {
        float sc = __fsub_rn(cnp[j], __fmul_rn(2.0f, acc[j]));  // f2 dropped: constant per row
        if (sc < minv)       { min2v = minv; minv = sc; mini = gbase + j; }  // strict <: first idx wins
        else if (sc < min2v) { min2v = sc; }
    }
}

__global__ void __launch_bounds__(256) vq_main(
    const float* __restrict__ x,
    const float* __restrict__ dc0, const float* __restrict__ dc1,
    const float* __restrict__ dc2, const float* __restrict__ dc3,
    float* __restrict__ ws, float* __restrict__ out)
{
    __shared__ double lred[4][4];          // [wave][dict] loss partials (8B-aligned first)
    __shared__ float  xs[RPB * 256];       // swizzled x tile
    __shared__ float  wminv[4][64][4];     // [dict][row][wave]
    __shared__ float  wmin2[4][64][4];
    __shared__ int    wmini[4][64][4];
    __shared__ int    kfin[4][64];         // packed winning col per [dict][row]
    __shared__ int    rep_list[256];
    __shared__ int    rep_cnt;

    const int tid  = threadIdx.x;
    const int lane = tid & 63;
    const int wv   = __builtin_amdgcn_readfirstlane(tid >> 6);
    const size_t rowbase = (size_t)blockIdx.x * RPB;

    if (tid == 0) rep_cnt = 0;

    // Stage x tile, swizzled
    for (int r = 0; r < RPB; ++r)
        xs[xs_idx(r, tid)] = x[(rowbase + r) * D + tid];
    __syncthreads();

    const float* xb = xs + lane * 256;     // lane = row
    const int    xc = lane & 31;
    const int  wv16 = wv * 16;

    float mv0 = FLT_MAX, mv1 = FLT_MAX, mv2 = FLT_MAX, mv3 = FLT_MAX;
    float m20 = FLT_MAX, m21 = FLT_MAX, m22 = FLT_MAX, m23 = FLT_MAX;
    int   mi0 = 0, mi1 = 0, mi2 = 0, mi3 = 0;

    chunk_min<64>(dc0, wv16, xb, xc, ws + 4 + wv16, mv0, mi0, m20, wv16);
    for (int cb = 0; cb < 128; cb += 64)
        chunk_min<128>(dc1, cb + wv16, xb, xc, ws + 4 + 64 + cb + wv16, mv1, mi1, m21, 64 + cb + wv16);
    for (int cb = 0; cb < 256; cb += 64)
        chunk_min<256>(dc2, cb + wv16, xb, xc, ws + 4 + 192 + cb + wv16, mv2, mi2, m22, 192 + cb + wv16);
    for (int cb = 0; cb < 512; cb += 64)
        chunk_min<512>(dc3, cb + wv16, xb, xc, ws + 4 + 448 + cb + wv16, mv3, mi3, m23, 448 + cb + wv16);

    wminv[0][lane][wv] = mv0; wmini[0][lane][wv] = mi0; wmin2[0][lane][wv] = m20;
    wminv[1][lane][wv] = mv1; wmini[1][lane][wv] = mi1; wmin2[1][lane][wv] = m21;
    wminv[2][lane][wv] = mv2; wmini[2][lane][wv] = mi2; wmin2[2][lane][wv] = m22;
    wminv[3][lane][wv] = mv3; wmini[3][lane][wv] = mi3; wmin2[3][lane][wv] = m23;
    __syncthreads();

    // Cross-wave two-min combine: 256 threads = 64 rows x 4 dicts
    {
        int i = tid >> 6, r = tid & 63;
        float bv = wminv[i][r][0]; int bi = wmini[i][r][0]; float b2 = wmin2[i][r][0];
#pragma unroll
        for (int w = 1; w < 4; ++w) {
            float v1 = wminv[i][r][w]; int i1 = wmini[i][r][w]; float v2 = wmin2[i][r][w];
            if (v1 < bv || (v1 == bv && i1 < bi)) { b2 = fminf(bv, v2); bv = v1; bi = i1; }
            else                                  { b2 = fminf(b2, v1); }
        }
        kfin[i][r] = bi;
        if (b2 - bv < EPS_GAP) {               // near-tie: quantization may decide -> np-mimic re-rank
            int p = atomicAdd(&rep_cnt, 1);
            rep_list[p] = (i << 6) | r;
        }
    }
    __syncthreads();

    // np-mimic re-rank: one wave per flagged (dict,row). Reproduce numpy fp32:
    //   dist[c] = fl( fl(f2 + c2[c]) - 2*sim[c] ),  argmin first-index-wins.
    // f2: any fp32 value within ~1 ULP of numpy's works (grid-translation commutes with
    // rounding inside a binade) -> use fp32(exact fp64 sum). c2: numpy axis-0 reduce is
    // SEQUENTIAL fp32. sim: fp32(exact fp64 dot) ~= correctly-rounded sgemm.
    for (int t = wv; t < rep_cnt; t += 4) {
        int e = rep_list[t];
        int i = e >> 6, r = e & 63;
        const float* dic; int K, base;
        if      (i == 0) { dic = dc0; K = 64;  base = 0;   }
        else if (i == 1) { dic = dc1; K = 128; base = 64;  }
        else if (i == 2) { dic = dc2; K = 256; base = 448 - 256; } // 192
        else             { dic = dc3; K = 512; base = 448; }
        double f2d = 0.0;
        for (int d = 0; d < D; ++d) {
            double xv = (double)xs[xs_idx(r, d)];
            f2d = fma(xv, xv, f2d);
        }
        const float f2 = (float)f2d;
        float bestv = FLT_MAX; int besti = 0x7fffffff;
        for (int c = lane; c < K; c += 64) {
            float  c2  = 0.0f;
            double smd = 0.0;
            for (int d = 0; d < D; ++d) {
                float bv = dic[d * K + c];
                c2  = __fadd_rn(c2, __fmul_rn(bv, bv));
                smd = fma((double)xs[xs_idx(r, d)], (double)bv, smd);
            }
            float sim  = (float)smd;
            float dist = __fsub_rn(__fadd_rn(f2, c2), __fmul_rn(2.0f, sim));
            if (dist < bestv) { bestv = dist; besti = c; }   // ascending c: keep-first
        }
#pragma unroll
        for (int off = 32; off; off >>= 1) {
            float ov = __shfl_xor(bestv, off);
            int   oi = __shfl_xor(besti, off);
            if (ov < bestv || (ov == bestv && oi < besti)) { bestv = ov; besti = oi; }
        }
        if (lane == 0) kfin[i][r] = base + besti;
    }
    __syncthreads();

    // Gather + weighted output (mimic np fp32 op order) + fp64 loss
    const float a0 = ws[0], a1 = ws[1], a2 = ws[2], a3 = ws[3];
    const float* dT = ws + 1024;
    double l0 = 0.0, l1 = 0.0, l2 = 0.0, l3 = 0.0;
    for (int r = 0; r < RPB; ++r) {
        const int i0 = kfin[0][r], i1 = kfin[1][r], i2 = kfin[2][r], i3 = kfin[3][r];
        const float xv = xs[xs_idx(r, tid)];
        const float q0 = dT[(size_t)i0 * D + tid];
        const float q1 = dT[(size_t)i1 * D + tid];
        const float q2 = dT[(size_t)i2 * D + tid];
        const float q3 = dT[(size_t)i3 * D + tid];
        float wq = __fadd_rn(__fadd_rn(__fadd_rn(__fmul_rn(a0, q0), __fmul_rn(a1, q1)),
                                       __fmul_rn(a2, q2)), __fmul_rn(a3, q3));
        out[(rowbase + r) * D + tid] = __fadd_rn(xv, __fsub_rn(wq, xv));   // x + sg(wq - x)
        const float e0 = xv - q0, e1 = xv - q1, e2 = xv - q2, e3 = xv - q3;
        l0 = fma((double)e0, (double)e0, l0);
        l1 = fma((double)e1, (double)e1, l1);
        l2 = fma((double)e2, (double)e2, l2);
        l3 = fma((double)e3, (double)e3, l3);
    }
#pragma unroll
    for (int off = 32; off; off >>= 1) {
        l0 += __shfl_down(l0, off); l1 += __shfl_down(l1, off);
        l2 += __shfl_down(l2, off); l3 += __shfl_down(l3, off);
    }
    if (lane == 0) { lred[wv][0] = l0; lred[wv][1] = l1; lred[wv][2] = l2; lred[wv][3] = l3; }
    __syncthreads();
    if (tid == 0) {
        double* lacc = (double*)(ws + 968);
#pragma unroll
        for (int i = 0; i < 4; ++i)
            atomicAdd(lacc + i, lred[0][i] + lred[1][i] + lred[2][i] + lred[3][i]);
    }
}

__global__ void vq_fin(const float* __restrict__ ws, float* __restrict__ out)
{
    if (threadIdx.x == 0) {
        const double* lacc = (const double*)(ws + 968);
        const double* dal  = (const double*)(ws + 976);
        double s = 0.0;
#pragma unroll
        for (int i = 0; i < 4; ++i)
            s += (lacc[i] * (1.0 / 16777216.0)) * dal[i];
        out[16777216] = (float)(s + 0.25 * s);
    }
}

extern "C" void kernel_launch(void* const* d_in, const int* in_sizes, int n_in,
                              void* d_out, int out_size, void* d_ws, size_t ws_size,
                              hipStream_t stream)
{
    const float* x   = (const float*)d_in[0];
    const float* av  = (const float*)d_in[1];
    const float* dc0 = (const float*)d_in[2];
    const float* dc1 = (const float*)d_in[3];
    const float* dc2 = (const float*)d_in[4];
    const float* dc3 = (const float*)d_in[5];
    float* out = (float*)d_out;
    float* ws  = (float*)d_ws;

    hipLaunchKernelGGL(vq_prep, dim3(4), dim3(256), 0, stream, av, dc0, dc1, dc2, dc3, ws);
    hipLaunchKernelGGL(vq_main, dim3(NROWS / RPB), dim3(256), 0, stream,
                       x, dc0, dc1, dc2, dc3, ws, out);
    hipLaunchKernelGGL(vq_fin, dim3(1), dim3(64), 0, stream, ws, out);
}

// Round 4
// 469.757 us; speedup vs baseline: 1.7845x; 1.7845x over previous
//
#include <hip/hip_runtime.h>
#include <float.h>
#include <math.h>

#define D 256
#define NROWS 65536
#define RPB 64
#define EPS_GAP 5e-4f
#define WSFRAG 1024      // float offset of bf16 fragment area in ws

// ws float layout:
//  [0..3]     alpha (float)
//  [4..963]   packed col norms ||c||^2 (packed order: d0[0,64) d1[64,192) d2[192,448) d3[448,960))
//  [968..975] 4 doubles: per-dict loss accumulators
//  [976..983] 4 doubles: alpha fp64
//  [1024..]   dict fragments: ushort[30 tiles][16 ksteps][2 splits][64 lanes][8], hi=split0 lo=split1
//             (983040 B = 245760 floats -> same ws footprint as R3)

typedef __attribute__((ext_vector_type(8)))  short short8v;   // 8 bf16 (4 VGPR) MFMA operand
typedef __attribute__((ext_vector_type(16))) float f32x16;    // 32x32 accumulator
typedef __attribute__((ext_vector_type(4)))  float float4v;

__device__ __forceinline__ ushort f2bf(float v) {             // RNE f32 -> bf16
    uint u = __float_as_uint(v);
    u += 0x7fffu + ((u >> 16) & 1u);
    return (ushort)(u >> 16);
}
__device__ __forceinline__ float bf2f(ushort u) { return __uint_as_float(((uint)u) << 16); }

// fragment ushort index: tile ct, col-in-tile c, kstep s, k-half, j=k&7, split p
__device__ __forceinline__ int fidx(int ct, int c, int s, int half, int j, int p) {
    return ((ct * 16 + s) * 2 + p) * 512 + (c + 32 * half) * 8 + j;
}
// reconstruct fp32 dict value (hi+lo, error ~2e-8 << thresholds)
__device__ __forceinline__ float dget(const ushort* fr, int pc, int d) {
    int b = fidx(pc >> 5, pc & 31, d >> 4, (d >> 3) & 1, d & 7, 0);
    return bf2f(fr[b]) + bf2f(fr[b + 512]);
}
__device__ __forceinline__ void dic_sel(int pc, const float* dc0, const float* dc1,
                                        const float* dc2, const float* dc3,
                                        const float*& dic, int& K, int& kk) {
    if      (pc < 64)  { dic = dc0; K = 64;  kk = pc;       }
    else if (pc < 192) { dic = dc1; K = 128; kk = pc - 64;  }
    else if (pc < 448) { dic = dc2; K = 256; kk = pc - 192; }
    else               { dic = dc3; K = 512; kk = pc - 448; }
}

__global__ void vq_prep(const float* __restrict__ av,
                        const float* __restrict__ dc0, const float* __restrict__ dc1,
                        const float* __restrict__ dc2, const float* __restrict__ dc3,
                        float* __restrict__ ws)
{
    int t = blockIdx.x * 256 + threadIdx.x;
    ushort* fr = (ushort*)(ws + WSFRAG);
    if (t == 0) {
        double x0 = av[0], x1 = av[1], x2 = av[2], x3 = av[3];
        double m = fmax(fmax(x0, x1), fmax(x2, x3));
        double e0 = exp(x0 - m), e1 = exp(x1 - m), e2 = exp(x2 - m), e3 = exp(x3 - m);
        double inv = 1.0 / (e0 + e1 + e2 + e3);
        ws[0] = (float)(e0 * inv); ws[1] = (float)(e1 * inv);
        ws[2] = (float)(e2 * inv); ws[3] = (float)(e3 * inv);
        double* lacc = (double*)(ws + 968);
        lacc[0] = 0.0; lacc[1] = 0.0; lacc[2] = 0.0; lacc[3] = 0.0;
        double* dal = (double*)(ws + 976);
        dal[0] = e0 * inv; dal[1] = e1 * inv; dal[2] = e2 * inv; dal[3] = e3 * inv;
    }
    if (t < 960) {              // column norms (same arithmetic as R3 - passed)
        const float* dic; int K, kk;
        dic_sel(t, dc0, dc1, dc2, dc3, dic, K, kk);
        float s = 0.0f;
        for (int d = 0; d < D; ++d) { float v = dic[d * K + kk]; s = fmaf(v, v, s); }
        ws[4 + t] = s;
    }
    if (t < 7680) {             // fragment build: pc = t>>3, k-range = (t&7)*32 .. +32
        int pc = t >> 3;
        const float* dic; int K, kk;
        dic_sel(pc, dc0, dc1, dc2, dc3, dic, K, kk);
        int ct = pc >> 5, c = pc & 31;
        int kb = (t & 7) * 32;
        for (int k = kb; k < kb + 32; ++k) {
            float v = dic[k * K + kk];
            ushort hu = f2bf(v);
            ushort lu = f2bf(v - bf2f(hu));
            fr[fidx(ct, c, k >> 4, (k >> 3) & 1, k & 7, 0)] = hu;
            fr[fidx(ct, c, k >> 4, (k >> 3) & 1, k & 7, 1)] = lu;
        }
    }
}

__global__ void __launch_bounds__(256, 2) vq_main(
    const float* __restrict__ x,
    const float* __restrict__ dc0, const float* __restrict__ dc1,
    const float* __restrict__ dc2, const float* __restrict__ dc3,
    float* __restrict__ ws, float* __restrict__ out)
{
    __shared__ double lred[4][4];
    __shared__ __align__(16) ushort afrag[32768];   // 64 KB A fragments [rt2][s16][p2][lane64][8]
    __shared__ float stv1[5][64], stv2[5][64];      // running two-min per slot/row
    __shared__ int   sti[5][64];
    __shared__ int   kfin[4][64];
    __shared__ int   rep_list[256];
    __shared__ int   rep_cnt;

    const int tid  = threadIdx.x;
    const int lane = tid & 63;
    const int wv   = __builtin_amdgcn_readfirstlane(tid >> 6);
    const size_t rowbase = (size_t)blockIdx.x * RPB;

    if (tid == 0) rep_cnt = 0;
    for (int i = tid; i < 5 * 64; i += 256) {
        (&stv1[0][0])[i] = FLT_MAX; (&stv2[0][0])[i] = FLT_MAX; (&sti[0][0])[i] = 0x7fffffff;
    }

    // ---- Stage A fragments: x fp32 -> bf16 hi/lo in MFMA A-layout ----
    const float4v* x4 = (const float4v*)(x + rowbase * D);
    for (int it = 0; it < 16; ++it) {
        int f = it * 256 + tid;
        int row = f >> 6, q = f & 63, k0 = q * 4;
        float4v v = x4[row * 64 + q];
        ushort h[4], l[4];
#pragma unroll
        for (int i = 0; i < 4; ++i) {
            float vv = v[i];
            h[i] = f2bf(vv);
            l[i] = f2bf(vv - bf2f(h[i]));
        }
        int bh = fidx(row >> 5, row & 31, k0 >> 4, (k0 >> 3) & 1, k0 & 7, 0);
        uint* ah = (uint*)&afrag[bh];
        ah[0] = (uint)h[0] | ((uint)h[1] << 16);
        ah[1] = (uint)h[2] | ((uint)h[3] << 16);
        uint* al = (uint*)&afrag[bh + 512];
        al[0] = (uint)l[0] | ((uint)l[1] << 16);
        al[1] = (uint)l[2] | ((uint)l[3] << 16);
    }
    __syncthreads();

    // ---- GEMM phase: wave-per-dict col-tile groups (w0:6 tiles, w1..w3: 8 each) ----
    const ushort* bfr = (const ushort*)(ws + WSFRAG);
    const float*  c2  = ws + 4;
    const int ng = (wv == 0) ? 3 : 4;
    for (int g = 0; g < ng; ++g) {
        const int ct0  = (wv == 0) ? 2 * g : 6 + (wv - 1) * 8 + 2 * g;
        const int slot = (wv == 0) ? ((g == 0) ? 0 : 1) : wv + 1;

        f32x16 acc[2][2];
#pragma unroll
        for (int a = 0; a < 2; ++a)
#pragma unroll
            for (int b = 0; b < 2; ++b) acc[a][b] = (f32x16)(0.0f);

        short8v A[2][2][2], B[2][2][2];   // [buf][rt|ct][split]
#pragma unroll
        for (int rt = 0; rt < 2; ++rt)
#pragma unroll
            for (int p = 0; p < 2; ++p)
                A[0][rt][p] = *(const short8v*)&afrag[((rt * 16 + 0) * 2 + p) * 512 + lane * 8];
#pragma unroll
        for (int cc = 0; cc < 2; ++cc)
#pragma unroll
            for (int p = 0; p < 2; ++p)
                B[0][cc][p] = *(const short8v*)&bfr[(((ct0 + cc) * 16 + 0) * 2 + p) * 512 + lane * 8];

#pragma unroll 2
        for (int s = 0; s < 16; ++s) {
            const int cur = s & 1, nxt = cur ^ 1;
            if (s < 15) {
#pragma unroll
                for (int rt = 0; rt < 2; ++rt)
#pragma unroll
                    for (int p = 0; p < 2; ++p)
                        A[nxt][rt][p] = *(const short8v*)&afrag[((rt * 16 + s + 1) * 2 + p) * 512 + lane * 8];
#pragma unroll
                for (int cc = 0; cc < 2; ++cc)
#pragma unroll
                    for (int p = 0; p < 2; ++p)
                        B[nxt][cc][p] = *(const short8v*)&bfr[(((ct0 + cc) * 16 + s + 1) * 2 + p) * 512 + lane * 8];
            }
#pragma unroll
            for (int rt = 0; rt < 2; ++rt)
#pragma unroll
                for (int cc = 0; cc < 2; ++cc) {
                    acc[rt][cc] = __builtin_amdgcn_mfma_f32_32x32x16_bf16(A[cur][rt][0], B[cur][cc][0], acc[rt][cc], 0, 0, 0);
                    acc[rt][cc] = __builtin_amdgcn_mfma_f32_32x32x16_bf16(A[cur][rt][1], B[cur][cc][0], acc[rt][cc], 0, 0, 0);
                    acc[rt][cc] = __builtin_amdgcn_mfma_f32_32x32x16_bf16(A[cur][rt][0], B[cur][cc][1], acc[rt][cc], 0, 0, 0);
                }
        }

        // ---- scores + per-row two-min (2 col-tiles merged, then 32-lane butterfly) ----
        const int   cA  = ct0 * 32 + (lane & 31);
        const float c2A = c2[cA], c2B = c2[cA + 32];
        const int   half = lane >> 5;
#pragma unroll
        for (int rt = 0; rt < 2; ++rt) {
#pragma unroll
            for (int reg = 0; reg < 16; ++reg) {
                float sA = fmaf(-2.0f, acc[rt][0][reg], c2A);
                float sB = fmaf(-2.0f, acc[rt][1][reg], c2B);
                float v1, v2; int i1;
                if (sB < sA) { v1 = sB; i1 = cA + 32; v2 = sA; }
                else         { v1 = sA; i1 = cA;      v2 = sB; }
#pragma unroll
                for (int off = 1; off <= 16; off <<= 1) {
                    float ov1 = __shfl_xor(v1, off);
                    int   oi1 = __shfl_xor(i1, off);
                    float ov2 = __shfl_xor(v2, off);
                    if (ov1 < v1 || (ov1 == v1 && oi1 < i1)) { v2 = fminf(v1, ov2); v1 = ov1; i1 = oi1; }
                    else                                     { v2 = fminf(v2, ov1); }
                }
                if ((lane & 31) == reg) {   // 2 lanes (halves) merge distinct rows -> no race
                    int row = rt * 32 + (reg & 3) + 8 * (reg >> 2) + 4 * half;
                    float s1 = stv1[slot][row]; int si1 = sti[slot][row];
                    if (v1 < s1 || (v1 == s1 && i1 < si1)) {
                        stv2[slot][row] = fminf(s1, v2);
                        stv1[slot][row] = v1; sti[slot][row] = i1;
                    } else {
                        stv2[slot][row] = fminf(stv2[slot][row], v1);
                    }
                }
            }
        }
    }
    __syncthreads();

    // ---- combine slots -> kfin + near-tie flags ----
    {
        int i = tid >> 6, r = tid & 63;
        float v1, v2; int i1;
        if (i < 3) { v1 = stv1[i][r]; v2 = stv2[i][r]; i1 = sti[i][r]; }
        else {
            float p1 = stv1[3][r], p2 = stv2[3][r]; int pi = sti[3][r];
            float q1 = stv1[4][r], q2 = stv2[4][r]; int qi = sti[4][r];
            if (q1 < p1) { v1 = q1; i1 = qi; v2 = fminf(p1, q2); }
            else         { v1 = p1; i1 = pi; v2 = fminf(q1, p2); }   // tie -> slot3 (lower cols)
        }
        kfin[i][r] = i1;
        if (v2 - v1 < EPS_GAP) { int p = atomicAdd(&rep_cnt, 1); rep_list[p] = (i << 6) | r; }
    }
    __syncthreads();

    // ---- np-mimic re-rank of flagged (dict,row) — identical semantics to R3 (passed) ----
    for (int t = wv; t < rep_cnt; t += 4) {
        int e = rep_list[t];
        int i = e >> 6, r = e & 63;
        const float* dic; int K, base;
        if      (i == 0) { dic = dc0; K = 64;  base = 0;   }
        else if (i == 1) { dic = dc1; K = 128; base = 64;  }
        else if (i == 2) { dic = dc2; K = 256; base = 192; }
        else             { dic = dc3; K = 512; base = 448; }
        const float* xrow = x + (rowbase + r) * D;
        double f2d = 0.0;
        for (int d = 0; d < D; ++d) { double xv = (double)xrow[d]; f2d = fma(xv, xv, f2d); }
        const float f2 = (float)f2d;
        float bestv = FLT_MAX; int besti = 0x7fffffff;
        for (int c = lane; c < K; c += 64) {
            float  cn  = 0.0f;
            double smd = 0.0;
            for (int d = 0; d < D; ++d) {
                float bv = dic[d * K + c];
                cn  = __fadd_rn(cn, __fmul_rn(bv, bv));
                smd = fma((double)xrow[d], (double)bv, smd);
            }
            float sim  = (float)smd;
            float dist = __fsub_rn(__fadd_rn(f2, cn), __fmul_rn(2.0f, sim));
            if (dist < bestv) { bestv = dist; besti = c; }
        }
#pragma unroll
        for (int off = 32; off; off >>= 1) {
            float ov = __shfl_xor(bestv, off);
            int   oi = __shfl_xor(besti, off);
            if (ov < bestv || (ov == bestv && oi < besti)) { bestv = ov; besti = oi; }
        }
        if (lane == 0) kfin[i][r] = base + besti;
    }
    __syncthreads();

    // ---- epilogue: gather (hi+lo reconstruct) + output + fp64 loss ----
    const float a0 = ws[0], a1 = ws[1], a2 = ws[2], a3 = ws[3];
    double l0 = 0.0, l1 = 0.0, l2 = 0.0, l3 = 0.0;
    for (int r = 0; r < RPB; ++r) {
        const float xv = x[(rowbase + r) * D + tid];
        const float q0 = dget(bfr, kfin[0][r], tid);
        const float q1 = dget(bfr, kfin[1][r], tid);
        const float q2 = dget(bfr, kfin[2][r], tid);
        const float q3 = dget(bfr, kfin[3][r], tid);
        float wq = __fadd_rn(__fadd_rn(__fadd_rn(__fmul_rn(a0, q0), __fmul_rn(a1, q1)),
                                       __fmul_rn(a2, q2)), __fmul_rn(a3, q3));
        out[(rowbase + r) * D + tid] = __fadd_rn(xv, __fsub_rn(wq, xv));
        const float e0 = xv - q0, e1 = xv - q1, e2 = xv - q2, e3 = xv - q3;
        l0 = fma((double)e0, (double)e0, l0);
        l1 = fma((double)e1, (double)e1, l1);
        l2 = fma((double)e2, (double)e2, l2);
        l3 = fma((double)e3, (double)e3, l3);
    }
#pragma unroll
    for (int off = 32; off; off >>= 1) {
        l0 += __shfl_down(l0, off); l1 += __shfl_down(l1, off);
        l2 += __shfl_down(l2, off); l3 += __shfl_down(l3, off);
    }
    if (lane == 0) { lred[wv][0] = l0; lred[wv][1] = l1; lred[wv][2] = l2; lred[wv][3] = l3; }
    __syncthreads();
    if (tid == 0) {
        double* lacc = (double*)(ws + 968);
#pragma unroll
        for (int i = 0; i < 4; ++i)
            atomicAdd(lacc + i, lred[0][i] + lred[1][i] + lred[2][i] + lred[3][i]);
    }
}

__global__ void vq_fin(const float* __restrict__ ws, float* __restrict__ out)
{
    if (threadIdx.x == 0) {
        const double* lacc = (const double*)(ws + 968);
        const double* dal  = (const double*)(ws + 976);
        double s = 0.0;
#pragma unroll
        for (int i = 0; i < 4; ++i) s += (lacc[i] * (1.0 / 16777216.0)) * dal[i];
        out[16777216] = (float)(s + 0.25 * s);
    }
}

extern "C" void kernel_launch(void* const* d_in, const int* in_sizes, int n_in,
                              void* d_out, int out_size, void* d_ws, size_t ws_size,
                              hipStream_t stream)
{
    const float* x   = (const float*)d_in[0];
    const float* av  = (const float*)d_in[1];
    const float* dc0 = (const float*)d_in[2];
    const float* dc1 = (const float*)d_in[3];
    const float* dc2 = (const float*)d_in[4];
    const float* dc3 = (const float*)d_in[5];
    float* out = (float*)d_out;
    float* ws  = (float*)d_ws;

    hipLaunchKernelGGL(vq_prep, dim3(30), dim3(256), 0, stream, av, dc0, dc1, dc2, dc3, ws);
    hipLaunchKernelGGL(vq_main, dim3(NROWS / RPB), dim3(256), 0, stream,
                       x, dc0, dc1, dc2, dc3, ws, out);
    hipLaunchKernelGGL(vq_fin, dim3(1), dim3(64), 0, stream, ws, out);
}

// Round 5
// 452.637 us; speedup vs baseline: 1.8520x; 1.0378x over previous
//
#include <hip/hip_runtime.h>
#include <float.h>
#include <math.h>

#define D 256
#define NROWS 65536
#define RPB 64
#define EPS_GAP 5e-4f
#define WSFRAG 1024
#define ASTRIDE 520    // ushorts per (rt,s,p) LDS fragment block: 512 + 8 pad (breaks 1024B bank alias)

// ws float layout:
//  [0..3]     alpha (float)
//  [4..963]   packed col norms ||c||^2 (packed order: d0[0,64) d1[64,192) d2[192,448) d3[448,960))
//  [968..975] 4 doubles: per-dict loss accumulators
//  [976..983] 4 doubles: alpha fp64
//  [1024..]   dict fragments: ushort[30 tiles][16 ksteps][2 splits][64 lanes][8] (stride 512, unchanged)

typedef __attribute__((ext_vector_type(8)))  short short8v;
typedef __attribute__((ext_vector_type(16))) float f32x16;
typedef __attribute__((ext_vector_type(4)))  float float4v;
typedef __attribute__((ext_vector_type(4)))  uint  uint4v;

__device__ __forceinline__ ushort f2bf(float v) {
    uint u = __float_as_uint(v);
    u += 0x7fffu + ((u >> 16) & 1u);
    return (ushort)(u >> 16);
}
__device__ __forceinline__ float bf2f(ushort u) { return __uint_as_float(((uint)u) << 16); }

__device__ __forceinline__ int fidx(int ct, int c, int s, int half, int j, int p) {
    return ((ct * 16 + s) * 2 + p) * 512 + (c + 32 * half) * 8 + j;   // global (ws) layout
}
__device__ __forceinline__ float dget(const ushort* fr, int pc, int d) {
    int b = fidx(pc >> 5, pc & 31, d >> 4, (d >> 3) & 1, d & 7, 0);
    return bf2f(fr[b]) + bf2f(fr[b + 512]);
}
__device__ __forceinline__ void dic_sel(int pc, const float* dc0, const float* dc1,
                                        const float* dc2, const float* dc3,
                                        const float*& dic, int& K, int& kk) {
    if      (pc < 64)  { dic = dc0; K = 64;  kk = pc;       }
    else if (pc < 192) { dic = dc1; K = 128; kk = pc - 64;  }
    else if (pc < 448) { dic = dc2; K = 256; kk = pc - 192; }
    else               { dic = dc3; K = 512; kk = pc - 448; }
}

__global__ void vq_prep(const float* __restrict__ av,
                        const float* __restrict__ dc0, const float* __restrict__ dc1,
                        const float* __restrict__ dc2, const float* __restrict__ dc3,
                        float* __restrict__ ws)
{
    int t = blockIdx.x * 256 + threadIdx.x;
    ushort* fr = (ushort*)(ws + WSFRAG);
    if (t == 0) {
        double x0 = av[0], x1 = av[1], x2 = av[2], x3 = av[3];
        double m = fmax(fmax(x0, x1), fmax(x2, x3));
        double e0 = exp(x0 - m), e1 = exp(x1 - m), e2 = exp(x2 - m), e3 = exp(x3 - m);
        double inv = 1.0 / (e0 + e1 + e2 + e3);
        ws[0] = (float)(e0 * inv); ws[1] = (float)(e1 * inv);
        ws[2] = (float)(e2 * inv); ws[3] = (float)(e3 * inv);
        double* lacc = (double*)(ws + 968);
        lacc[0] = 0.0; lacc[1] = 0.0; lacc[2] = 0.0; lacc[3] = 0.0;
        double* dal = (double*)(ws + 976);
        dal[0] = e0 * inv; dal[1] = e1 * inv; dal[2] = e2 * inv; dal[3] = e3 * inv;
    }
    if (t < 960) {
        const float* dic; int K, kk;
        dic_sel(t, dc0, dc1, dc2, dc3, dic, K, kk);
        float s = 0.0f;
        for (int d = 0; d < D; ++d) { float v = dic[d * K + kk]; s = fmaf(v, v, s); }
        ws[4 + t] = s;
    }
    if (t < 7680) {
        int pc = t >> 3;
        const float* dic; int K, kk;
        dic_sel(pc, dc0, dc1, dc2, dc3, dic, K, kk);
        int ct = pc >> 5, c = pc & 31;
        int kb = (t & 7) * 32;
        for (int k = kb; k < kb + 32; ++k) {
            float v = dic[k * K + kk];
            ushort hu = f2bf(v);
            ushort lu = f2bf(v - bf2f(hu));
            fr[fidx(ct, c, k >> 4, (k >> 3) & 1, k & 7, 0)] = hu;
            fr[fidx(ct, c, k >> 4, (k >> 3) & 1, k & 7, 1)] = lu;
        }
    }
}

__device__ __forceinline__ void load_B(short8v (&B)[2][2], const ushort* bfr, int ct0, int s, int lane) {
#pragma unroll
    for (int cc = 0; cc < 2; ++cc)
#pragma unroll
        for (int p = 0; p < 2; ++p)
            B[cc][p] = *(const short8v*)&bfr[(((ct0 + cc) * 16 + s) * 2 + p) * 512 + lane * 8];
}
__device__ __forceinline__ void load_A(short8v (&A)[2][2], const ushort* af, int s, int lane) {
#pragma unroll
    for (int rt = 0; rt < 2; ++rt)
#pragma unroll
        for (int p = 0; p < 2; ++p)
            A[rt][p] = *(const short8v*)&af[((rt * 16 + s) * 2 + p) * ASTRIDE + lane * 8];
}

__global__ void __launch_bounds__(256, 2) vq_main(
    const float* __restrict__ x,
    const float* __restrict__ dc0, const float* __restrict__ dc1,
    const float* __restrict__ dc2, const float* __restrict__ dc3,
    float* __restrict__ ws, float* __restrict__ out)
{
    __shared__ double lred[4][4];
    __shared__ __align__(16) ushort afrag[64 * ASTRIDE];   // 66560 B
    __shared__ float stv1[5][64], stv2[5][64];
    __shared__ int   sti[5][64];
    __shared__ int   kfin[4][64];
    __shared__ int   rep_list[256];
    __shared__ int   rep_cnt;

    const int tid  = threadIdx.x;
    const int lane = tid & 63;
    const int wv   = __builtin_amdgcn_readfirstlane(tid >> 6);
    const int lcol = lane & 31, half = lane >> 5;
    const size_t rowbase = (size_t)blockIdx.x * RPB;

    if (tid == 0) rep_cnt = 0;

    // ---- Stage A: x -> bf16 hi/lo fragments, b128 writes (conflict-reduced via ASTRIDE pad) ----
    const float4v* x4 = (const float4v*)(x + rowbase * D);
    for (int it = 0; it < 8; ++it) {
        int f = it * 256 + tid;                 // b128-unit id in [0,2048)
        int row = f >> 5, sh = f & 31, s = sh >> 1, hf = sh & 1;
        float4v va = x4[row * 64 + s * 4 + hf * 2];
        float4v vb = x4[row * 64 + s * 4 + hf * 2 + 1];
        ushort h[8], l[8];
#pragma unroll
        for (int i = 0; i < 4; ++i) {
            float u = va[i], w = vb[i];
            h[i]     = f2bf(u); l[i]     = f2bf(u - bf2f(h[i]));
            h[4 + i] = f2bf(w); l[4 + i] = f2bf(w - bf2f(h[4 + i]));
        }
        int bu = (((row >> 5) * 16 + s) * 2 + 0) * ASTRIDE + ((row & 31) + 32 * hf) * 8;
        uint4v Hv = { (uint)h[0] | ((uint)h[1] << 16), (uint)h[2] | ((uint)h[3] << 16),
                      (uint)h[4] | ((uint)h[5] << 16), (uint)h[6] | ((uint)h[7] << 16) };
        uint4v Lv = { (uint)l[0] | ((uint)l[1] << 16), (uint)l[2] | ((uint)l[3] << 16),
                      (uint)l[4] | ((uint)l[5] << 16), (uint)l[6] | ((uint)l[7] << 16) };
        *(uint4v*)&afrag[bu]           = Hv;    // p=0 (hi)
        *(uint4v*)&afrag[bu + ASTRIDE] = Lv;    // p=1 (lo)
    }
    __syncthreads();

    // ---- GEMM phase: register running two-min, flush only at dict boundaries ----
    const ushort* bfr = (const ushort*)(ws + WSFRAG);
    const float*  c2  = ws + 4;

    float rv1[2][16], rv2[2][16];
    uint  tp[2][3];                 // packed 5-bit winning-tile per (rt,reg): reg r -> word r/6, shift (r%6)*5
#pragma unroll
    for (int rt = 0; rt < 2; ++rt) {
#pragma unroll
        for (int r = 0; r < 16; ++r) { rv1[rt][r] = FLT_MAX; rv2[rt][r] = FLT_MAX; }
        tp[rt][0] = 0; tp[rt][1] = 0; tp[rt][2] = 0;
    }

    const int ngroups = (wv == 0) ? 3 : 4;
    for (int g = 0; g < ngroups; ++g) {
        const int ct0 = (wv == 0) ? 2 * g : 6 + (wv - 1) * 8 + 2 * g;

        f32x16 acc[2][2];
#pragma unroll
        for (int a = 0; a < 2; ++a)
#pragma unroll
            for (int b = 0; b < 2; ++b) acc[a][b] = (f32x16)(0.0f);

        short8v A[2][2][2], B[3][2][2];
        load_B(B[0], bfr, ct0, 0, lane);
        load_B(B[1], bfr, ct0, 1, lane);
        load_A(A[0], afrag, 0, lane);

#pragma unroll
        for (int s = 0; s < 16; ++s) {
            if (s < 14) load_B(B[(s + 2) % 3], bfr, ct0, s + 2, lane);
            if (s < 15) load_A(A[(s + 1) & 1], afrag, s + 1, lane);
            const int bi = s % 3, ai = s & 1;
#pragma unroll
            for (int rt = 0; rt < 2; ++rt)
#pragma unroll
                for (int cc = 0; cc < 2; ++cc) {
                    acc[rt][cc] = __builtin_amdgcn_mfma_f32_32x32x16_bf16(A[ai][rt][0], B[bi][cc][0], acc[rt][cc], 0, 0, 0);
                    acc[rt][cc] = __builtin_amdgcn_mfma_f32_32x32x16_bf16(A[ai][rt][1], B[bi][cc][0], acc[rt][cc], 0, 0, 0);
                    acc[rt][cc] = __builtin_amdgcn_mfma_f32_32x32x16_bf16(A[ai][rt][0], B[bi][cc][1], acc[rt][cc], 0, 0, 0);
                }
        }

        // scores + register two-min update (no cross-lane work here)
        const int   colA = ct0 * 32 + lcol;
        const float c2A  = c2[colA], c2B = c2[colA + 32];
#pragma unroll
        for (int rt = 0; rt < 2; ++rt)
#pragma unroll
            for (int r = 0; r < 16; ++r) {
                float sA = fmaf(-2.0f, acc[rt][0][r], c2A);
                float sB = fmaf(-2.0f, acc[rt][1][r], c2B);
                float v1, v2; uint ts;
                if (sB < sA) { v1 = sB; v2 = sA; ts = (uint)(ct0 + 1); }
                else         { v1 = sA; v2 = sB; ts = (uint)ct0; }
                const int w = r / 6, sh5 = (r % 6) * 5;
                if (v1 < rv1[rt][r]) {          // strict <: ties keep older (lower col) winner
                    rv2[rt][r] = fminf(rv1[rt][r], v2);
                    rv1[rt][r] = v1;
                    tp[rt][w]  = (tp[rt][w] & ~(31u << sh5)) | (ts << sh5);
                } else {
                    rv2[rt][r] = fminf(rv2[rt][r], v1);
                }
            }

        // flush at dict boundary: butterfly across the 32-lane half, store to this wave's slot
        const bool doflush = (wv == 0) ? (g == 0 || g == 2) : (g == 3);
        if (doflush) {
            const int slot = (wv == 0) ? ((g == 0) ? 0 : 1) : wv + 1;
#pragma unroll
            for (int rt = 0; rt < 2; ++rt)
#pragma unroll
                for (int r = 0; r < 16; ++r) {
                    float v1 = rv1[rt][r], v2 = rv2[rt][r];
                    int   i1 = (int)((tp[rt][r / 6] >> ((r % 6) * 5)) & 31u) * 32 + lcol;
#pragma unroll
                    for (int off = 1; off <= 16; off <<= 1) {
                        float ov1 = __shfl_xor(v1, off);
                        int   oi1 = __shfl_xor(i1, off);
                        float ov2 = __shfl_xor(v2, off);
                        if (ov1 < v1 || (ov1 == v1 && oi1 < i1)) { v2 = fminf(v1, ov2); v1 = ov1; i1 = oi1; }
                        else                                     { v2 = fminf(v2, ov1); }
                    }
                    if (lcol == r) {
                        int row = rt * 32 + (r & 3) + 8 * (r >> 2) + 4 * half;
                        stv1[slot][row] = v1; stv2[slot][row] = v2; sti[slot][row] = i1;
                    }
                    rv1[rt][r] = FLT_MAX; rv2[rt][r] = FLT_MAX;
                }
#pragma unroll
            for (int rt = 0; rt < 2; ++rt) { tp[rt][0] = 0; tp[rt][1] = 0; tp[rt][2] = 0; }
        }
    }
    __syncthreads();

    // ---- combine slots -> kfin + near-tie flags ----
    {
        int i = tid >> 6, r = tid & 63;
        float v1, v2; int i1;
        if (i < 3) { v1 = stv1[i][r]; v2 = stv2[i][r]; i1 = sti[i][r]; }
        else {
            float p1 = stv1[3][r], p2 = stv2[3][r]; int pi = sti[3][r];
            float q1 = stv1[4][r], q2 = stv2[4][r]; int qi = sti[4][r];
            if (q1 < p1) { v1 = q1; i1 = qi; v2 = fminf(p1, q2); }
            else         { v1 = p1; i1 = pi; v2 = fminf(q1, p2); }
        }
        kfin[i][r] = i1;
        if (v2 - v1 < EPS_GAP) { int p = atomicAdd(&rep_cnt, 1); rep_list[p] = (i << 6) | r; }
    }
    __syncthreads();

    // ---- np-mimic re-rank of flagged (dict,row) — identical semantics to R3/R4 (passed) ----
    for (int t = wv; t < rep_cnt; t += 4) {
        int e = rep_list[t];
        int i = e >> 6, r = e & 63;
        const float* dic; int K, base;
        if      (i == 0) { dic = dc0; K = 64;  base = 0;   }
        else if (i == 1) { dic = dc1; K = 128; base = 64;  }
        else if (i == 2) { dic = dc2; K = 256; base = 192; }
        else             { dic = dc3; K = 512; base = 448; }
        const float* xrow = x + (rowbase + r) * D;
        double f2d = 0.0;
        for (int d = 0; d < D; ++d) { double xv = (double)xrow[d]; f2d = fma(xv, xv, f2d); }
        const float f2 = (float)f2d;
        float bestv = FLT_MAX; int besti = 0x7fffffff;
        for (int c = lane; c < K; c += 64) {
            float  cn  = 0.0f;
            double smd = 0.0;
            for (int d = 0; d < D; ++d) {
                float bv = dic[d * K + c];
                cn  = __fadd_rn(cn, __fmul_rn(bv, bv));
                smd = fma((double)xrow[d], (double)bv, smd);
            }
            float sim  = (float)smd;
            float dist = __fsub_rn(__fadd_rn(f2, cn), __fmul_rn(2.0f, sim));
            if (dist < bestv) { bestv = dist; besti = c; }
        }
#pragma unroll
        for (int off = 32; off; off >>= 1) {
            float ov = __shfl_xor(bestv, off);
            int   oi = __shfl_xor(besti, off);
            if (ov < bestv || (ov == bestv && oi < besti)) { bestv = ov; besti = oi; }
        }
        if (lane == 0) kfin[i][r] = base + besti;
    }
    __syncthreads();

    // ---- epilogue: x from LDS hi/lo (err ~2e-8), q gathered hi+lo, fp64 loss ----
    const float a0 = ws[0], a1 = ws[1], a2 = ws[2], a3 = ws[3];
    double l0 = 0.0, l1 = 0.0, l2 = 0.0, l3 = 0.0;
    {
        const int s_e = tid >> 4, hf_e = (tid >> 3) & 1, j_e = tid & 7;
        for (int r = 0; r < RPB; ++r) {
            const int bu = (((r >> 5) * 16 + s_e) * 2 + 0) * ASTRIDE + ((r & 31) + 32 * hf_e) * 8 + j_e;
            const float xv = bf2f(afrag[bu]) + bf2f(afrag[bu + ASTRIDE]);
            const int i0 = kfin[0][r], i1 = kfin[1][r], i2 = kfin[2][r], i3 = kfin[3][r];
            const float q0 = dget(bfr, i0, tid);
            const float q1 = dget(bfr, i1, tid);
            const float q2 = dget(bfr, i2, tid);
            const float q3 = dget(bfr, i3, tid);
            float wq = __fadd_rn(__fadd_rn(__fadd_rn(__fmul_rn(a0, q0), __fmul_rn(a1, q1)),
                                           __fmul_rn(a2, q2)), __fmul_rn(a3, q3));
            out[(rowbase + r) * D + tid] = __fadd_rn(xv, __fsub_rn(wq, xv));
            const float e0 = xv - q0, e1 = xv - q1, e2 = xv - q2, e3 = xv - q3;
            l0 = fma((double)e0, (double)e0, l0);
            l1 = fma((double)e1, (double)e1, l1);
            l2 = fma((double)e2, (double)e2, l2);
            l3 = fma((double)e3, (double)e3, l3);
        }
    }
#pragma unroll
    for (int off = 32; off; off >>= 1) {
        l0 += __shfl_down(l0, off); l1 += __shfl_down(l1, off);
        l2 += __shfl_down(l2, off); l3 += __shfl_down(l3, off);
    }
    if (lane == 0) { lred[wv][0] = l0; lred[wv][1] = l1; lred[wv][2] = l2; lred[wv][3] = l3; }
    __syncthreads();
    if (tid == 0) {
        double* lacc = (double*)(ws + 968);
#pragma unroll
        for (int i = 0; i < 4; ++i)
            atomicAdd(lacc + i, lred[0][i] + lred[1][i] + lred[2][i] + lred[3][i]);
    }
}

__global__ void vq_fin(const float* __restrict__ ws, float* __restrict__ out)
{
    if (threadIdx.x == 0) {
        const double* lacc = (const double*)(ws + 968);
        const double* dal  = (const double*)(ws + 976);
        double s = 0.0;
#pragma unroll
        for (int i = 0; i < 4; ++i) s += (lacc[i] * (1.0 / 16777216.0)) * dal[i];
        out[16777216] = (float)(s + 0.25 * s);
    }
}

extern "C" void kernel_launch(void* const* d_in, const int* in_sizes, int n_in,
                              void* d_out, int out_size, void* d_ws, size_t ws_size,
                              hipStream_t stream)
{
    const float* x   = (const float*)d_in[0];
    const float* av  = (const float*)d_in[1];
    const float* dc0 = (const float*)d_in[2];
    const float* dc1 = (const float*)d_in[3];
    const float* dc2 = (const float*)d_in[4];
    const float* dc3 = (const float*)d_in[5];
    float* out = (float*)d_out;
    float* ws  = (float*)d_ws;

    hipLaunchKernelGGL(vq_prep, dim3(30), dim3(256), 0, stream, av, dc0, dc1, dc2, dc3, ws);
    hipLaunchKernelGGL(vq_main, dim3(NROWS / RPB), dim3(256), 0, stream,
                       x, dc0, dc1, dc2, dc3, ws, out);
    hipLaunchKernelGGL(vq_fin, dim3(1), dim3(64), 0, stream, ws, out);
}

// Round 6
// 403.623 us; speedup vs baseline: 2.0769x; 1.1214x over previous
//
#include <hip/hip_runtime.h>
#include <float.h>
#include <math.h>

#define D 256
#define NROWS 65536
#define RPB 64
#define EPS_CAND 2e-4f   // candidate threshold above per-(dict,row) min; covers np quantization 9.2e-5 + our err 4e-6
#define CAP 6            // max candidates per (dict,row); overflow -> full np-mimic fallback
#define WSFRAG 1024
#define ASTRIDE 520      // ushorts per (rt,s,p) LDS fragment block: 512 + 8 pad

// ws float layout:
//  [0..3]     alpha (float)
//  [4..963]   packed col norms ||c||^2, SEQUENTIAL UNFUSED fp32 (= numpy's axis-0 reduce)
//  [968..975] 4 doubles: per-dict loss accumulators
//  [976..983] 4 doubles: alpha fp64
//  [1024..]   dict fragments: ushort[30 tiles][16 ksteps][2 splits][64 lanes][8]

typedef __attribute__((ext_vector_type(8)))  short short8v;
typedef __attribute__((ext_vector_type(16))) float f32x16;
typedef __attribute__((ext_vector_type(4)))  float float4v;
typedef __attribute__((ext_vector_type(4)))  uint  uint4v;

__device__ __forceinline__ ushort f2bf(float v) {
    uint u = __float_as_uint(v);
    u += 0x7fffu + ((u >> 16) & 1u);
    return (ushort)(u >> 16);
}
__device__ __forceinline__ float bf2f(ushort u) { return __uint_as_float(((uint)u) << 16); }

__device__ __forceinline__ int fidx(int ct, int c, int s, int half, int j, int p) {
    return ((ct * 16 + s) * 2 + p) * 512 + (c + 32 * half) * 8 + j;   // ws (global) layout
}
__device__ __forceinline__ float dget(const ushort* fr, int pc, int d) {
    int b = fidx(pc >> 5, pc & 31, d >> 4, (d >> 3) & 1, d & 7, 0);
    return bf2f(fr[b]) + bf2f(fr[b + 512]);
}
// afrag (LDS) index of x[row][d], hi plane (lo at +ASTRIDE)
__device__ __forceinline__ int aidx(int row, int d) {
    return (((row >> 5) * 16 + (d >> 4)) * 2) * ASTRIDE + ((row & 31) + 32 * ((d >> 3) & 1)) * 8 + (d & 7);
}
__device__ __forceinline__ void dic_sel(int pc, const float* dc0, const float* dc1,
                                        const float* dc2, const float* dc3,
                                        const float*& dic, int& K, int& kk) {
    if      (pc < 64)  { dic = dc0; K = 64;  kk = pc;       }
    else if (pc < 192) { dic = dc1; K = 128; kk = pc - 64;  }
    else if (pc < 448) { dic = dc2; K = 256; kk = pc - 192; }
    else               { dic = dc3; K = 512; kk = pc - 448; }
}

__global__ void vq_prep(const float* __restrict__ av,
                        const float* __restrict__ dc0, const float* __restrict__ dc1,
                        const float* __restrict__ dc2, const float* __restrict__ dc3,
                        float* __restrict__ ws)
{
    int t = blockIdx.x * 256 + threadIdx.x;
    ushort* fr = (ushort*)(ws + WSFRAG);
    if (t == 0) {
        double x0 = av[0], x1 = av[1], x2 = av[2], x3 = av[3];
        double m = fmax(fmax(x0, x1), fmax(x2, x3));
        double e0 = exp(x0 - m), e1 = exp(x1 - m), e2 = exp(x2 - m), e3 = exp(x3 - m);
        double inv = 1.0 / (e0 + e1 + e2 + e3);
        ws[0] = (float)(e0 * inv); ws[1] = (float)(e1 * inv);
        ws[2] = (float)(e2 * inv); ws[3] = (float)(e3 * inv);
        double* lacc = (double*)(ws + 968);
        lacc[0] = 0.0; lacc[1] = 0.0; lacc[2] = 0.0; lacc[3] = 0.0;
        double* dal = (double*)(ws + 976);
        dal[0] = e0 * inv; dal[1] = e1 * inv; dal[2] = e2 * inv; dal[3] = e3 * inv;
    }
    if (t < 960) {   // np-exact column norms: sequential unfused fp32 (numpy axis-0 reduce)
        const float* dic; int K, kk;
        dic_sel(t, dc0, dc1, dc2, dc3, dic, K, kk);
        float s = 0.0f;
        for (int d = 0; d < D; ++d) { float v = dic[d * K + kk]; s = __fadd_rn(s, __fmul_rn(v, v)); }
        ws[4 + t] = s;
    }
    if (t < 7680) {
        int pc = t >> 3;
        const float* dic; int K, kk;
        dic_sel(pc, dc0, dc1, dc2, dc3, dic, K, kk);
        int ct = pc >> 5, c = pc & 31;
        int kb = (t & 7) * 32;
        for (int k = kb; k < kb + 32; ++k) {
            float v = dic[k * K + kk];
            ushort hu = f2bf(v);
            ushort lu = f2bf(v - bf2f(hu));
            fr[fidx(ct, c, k >> 4, (k >> 3) & 1, k & 7, 0)] = hu;
            fr[fidx(ct, c, k >> 4, (k >> 3) & 1, k & 7, 1)] = lu;
        }
    }
}

__device__ __forceinline__ void load_B(short8v (&B)[2][2], const ushort* bfr, int ct0, int s, int lane) {
#pragma unroll
    for (int cc = 0; cc < 2; ++cc)
#pragma unroll
        for (int p = 0; p < 2; ++p)
            B[cc][p] = *(const short8v*)&bfr[(((ct0 + cc) * 16 + s) * 2 + p) * 512 + lane * 8];
}
__device__ __forceinline__ void load_A(short8v (&A)[2][2], const ushort* af, int s, int lane) {
#pragma unroll
    for (int rt = 0; rt < 2; ++rt)
#pragma unroll
        for (int p = 0; p < 2; ++p)
            A[rt][p] = *(const short8v*)&af[((rt * 16 + s) * 2 + p) * ASTRIDE + lane * 8];
}

// One 2-col-tile group. emit(rt, reg, scA, scB) gets the two scores for this (rt,reg).
// MFMA order fixed by the acc dependence chain -> bitwise identical between passes.
template<class F>
__device__ __forceinline__ void gemm_group(const ushort* af, const ushort* bfr,
                                           int ct0, int lane, float c2A, float c2B, F&& emit)
{
    f32x16 acc[2][2];
#pragma unroll
    for (int a = 0; a < 2; ++a)
#pragma unroll
        for (int b = 0; b < 2; ++b) acc[a][b] = (f32x16)(0.0f);

    short8v A[2][2][2], B[2][2][2];
    load_A(A[0], af, 0, lane);
    load_B(B[0], bfr, ct0, 0, lane);
#pragma unroll
    for (int s = 0; s < 16; ++s) {
        if (s < 15) {
            load_A(A[(s + 1) & 1], af, s + 1, lane);
            load_B(B[(s + 1) & 1], bfr, ct0, s + 1, lane);
        }
        const int cur = s & 1;
#pragma unroll
        for (int rt = 0; rt < 2; ++rt)
#pragma unroll
            for (int cc = 0; cc < 2; ++cc) {
                acc[rt][cc] = __builtin_amdgcn_mfma_f32_32x32x16_bf16(A[cur][rt][0], B[cur][cc][0], acc[rt][cc], 0, 0, 0);
                acc[rt][cc] = __builtin_amdgcn_mfma_f32_32x32x16_bf16(A[cur][rt][1], B[cur][cc][0], acc[rt][cc], 0, 0, 0);
                acc[rt][cc] = __builtin_amdgcn_mfma_f32_32x32x16_bf16(A[cur][rt][0], B[cur][cc][1], acc[rt][cc], 0, 0, 0);
            }
    }
#pragma unroll
    for (int rt = 0; rt < 2; ++rt)
#pragma unroll
        for (int reg = 0; reg < 16; ++reg)
            emit(rt, reg, fmaf(-2.0f, acc[rt][0][reg], c2A), fmaf(-2.0f, acc[rt][1][reg], c2B));
}

__global__ void __launch_bounds__(256, 2) vq_main(
    const float* __restrict__ x,
    const float* __restrict__ dc0, const float* __restrict__ dc1,
    const float* __restrict__ dc2, const float* __restrict__ dc3,
    float* __restrict__ ws, float* __restrict__ out)
{
    __shared__ double lred[4][4];
    __shared__ __align__(16) ushort afrag[64 * ASTRIDE];   // 66560 B
    __shared__ float slotmin[5][64];      // pass-1 per-slot min value
    __shared__ float thrL[4][64];         // min1 + EPS_CAND
    __shared__ float f2row[64];
    __shared__ int   cnt[4][64];
    __shared__ int   cand[4][64][CAP];
    __shared__ int   kfin[4][64];
    __shared__ int   rep_list[64];
    __shared__ int   rep_cnt;

    const int tid  = threadIdx.x;
    const int lane = tid & 63;
    const int wv   = __builtin_amdgcn_readfirstlane(tid >> 6);
    const int lcol = lane & 31, half = lane >> 5;
    const size_t rowbase = (size_t)blockIdx.x * RPB;

    if (tid == 0) rep_cnt = 0;
    for (int i = tid; i < 256; i += 256) { (&cnt[0][0])[i] = 0; }

    // ---- Stage A: x -> bf16 hi/lo fragments (b128 writes) ----
    const float4v* x4 = (const float4v*)(x + rowbase * D);
    for (int it = 0; it < 8; ++it) {
        int f = it * 256 + tid;
        int row = f >> 5, sh = f & 31, s = sh >> 1, hf = sh & 1;
        float4v va = x4[row * 64 + s * 4 + hf * 2];
        float4v vb = x4[row * 64 + s * 4 + hf * 2 + 1];
        ushort h[8], l[8];
#pragma unroll
        for (int i = 0; i < 4; ++i) {
            float u = va[i], w = vb[i];
            h[i]     = f2bf(u); l[i]     = f2bf(u - bf2f(h[i]));
            h[4 + i] = f2bf(w); l[4 + i] = f2bf(w - bf2f(h[4 + i]));
        }
        int bu = (((row >> 5) * 16 + s) * 2) * ASTRIDE + ((row & 31) + 32 * hf) * 8;
        uint4v Hv = { (uint)h[0] | ((uint)h[1] << 16), (uint)h[2] | ((uint)h[3] << 16),
                      (uint)h[4] | ((uint)h[5] << 16), (uint)h[6] | ((uint)h[7] << 16) };
        uint4v Lv = { (uint)l[0] | ((uint)l[1] << 16), (uint)l[2] | ((uint)l[3] << 16),
                      (uint)l[4] | ((uint)l[5] << 16), (uint)l[6] | ((uint)l[7] << 16) };
        *(uint4v*)&afrag[bu]           = Hv;
        *(uint4v*)&afrag[bu + ASTRIDE] = Lv;
    }
    __syncthreads();

    // f2 per row (fp64 exact -> fp32; any fp32 value in the binade is grid-aligned)
    if (tid < 64) {
        double s = 0.0;
        for (int d0 = 0; d0 < D; d0 += 8) {
            int xb = aidx(tid, d0);
            short8v xh = *(const short8v*)&afrag[xb];
            short8v xl = *(const short8v*)&afrag[xb + ASTRIDE];
#pragma unroll
            for (int j = 0; j < 8; ++j) {
                double xv = (double)(bf2f((ushort)xh[j]) + bf2f((ushort)xl[j]));
                s = fma(xv, xv, s);
            }
        }
        f2row[tid] = (float)s;
    }

    const ushort* bfr = (const ushort*)(ws + WSFRAG);
    const float*  c2  = ws + 4;
    const int ngroups = (wv == 0) ? 3 : 4;

    // ---- pass 1: per-(dict,row) min value only ----
    {
        float rv1[2][16];
#pragma unroll
        for (int rt = 0; rt < 2; ++rt)
#pragma unroll
            for (int r = 0; r < 16; ++r) rv1[rt][r] = FLT_MAX;

        for (int g = 0; g < ngroups; ++g) {
            const int ct0 = (wv == 0) ? 2 * g : 6 + (wv - 1) * 8 + 2 * g;
            gemm_group(afrag, bfr, ct0, lane, c2[ct0 * 32 + lcol], c2[ct0 * 32 + 32 + lcol],
                [&](int rt, int reg, float sA, float sB) {
                    rv1[rt][reg] = fminf(rv1[rt][reg], fminf(sA, sB));
                });
            const bool doflush = (wv == 0) ? (g == 0 || g == 2) : (g == 3);
            if (doflush) {
                const int slot = (wv == 0) ? ((g == 0) ? 0 : 1) : wv + 1;
#pragma unroll
                for (int rt = 0; rt < 2; ++rt)
#pragma unroll
                    for (int r = 0; r < 16; ++r) {
                        float v = rv1[rt][r];
#pragma unroll
                        for (int off = 1; off <= 16; off <<= 1) v = fminf(v, __shfl_xor(v, off));
                        if (lcol == r)
                            slotmin[slot][rt * 32 + (r & 3) + 8 * (r >> 2) + 4 * half] = v;
                        rv1[rt][r] = FLT_MAX;
                    }
            }
        }
    }
    __syncthreads();

    // combine slots -> threshold
    {
        int i = tid >> 6, r = tid & 63;
        float m1 = (i < 3) ? slotmin[i][r] : fminf(slotmin[3][r], slotmin[4][r]);
        thrL[i][r] = m1 + EPS_CAND;
    }
    __syncthreads();

    // ---- pass 2: recompute scores (bitwise same), collect candidates ----
    for (int g = 0; g < ngroups; ++g) {
        const int ct0 = (wv == 0) ? 2 * g : 6 + (wv - 1) * 8 + 2 * g;
        const int dct = (wv == 0) ? ((g == 0) ? 0 : 1) : ((wv == 1) ? 2 : 3);
        gemm_group(afrag, bfr, ct0, lane, c2[ct0 * 32 + lcol], c2[ct0 * 32 + 32 + lcol],
            [&](int rt, int reg, float sA, float sB) {
                const int row = rt * 32 + (reg & 3) + 8 * (reg >> 2) + 4 * half;
                const float thr = thrL[dct][row];
                if (sA < thr) {
                    int pos = atomicAdd(&cnt[dct][row], 1);
                    if (pos < CAP) cand[dct][row][pos] = ct0 * 32 + lcol;
                }
                if (sB < thr) {
                    int pos = atomicAdd(&cnt[dct][row], 1);
                    if (pos < CAP) cand[dct][row][pos] = ct0 * 32 + 32 + lcol;
                }
            });
    }
    __syncthreads();

    // ---- final select: np-mimic among candidates (thread = (dict,row)) ----
    {
        const int i = tid >> 6, r = tid & 63;
        const int n = cnt[i][r];
        if (n > CAP) {
            int p = atomicAdd(&rep_cnt, 1);
            rep_list[p] = (i << 6) | r;
        } else {
            const float f2 = f2row[r];
            float best = FLT_MAX; int bi = 0x7fffffff;
            for (int j = 0; j < n; ++j) {
                const int pc = cand[i][r][j];
                double smd = 0.0;
                for (int d0 = 0; d0 < D; d0 += 8) {
                    int xb = aidx(r, d0);
                    short8v xh = *(const short8v*)&afrag[xb];
                    short8v xl = *(const short8v*)&afrag[xb + ASTRIDE];
                    int bb = fidx(pc >> 5, pc & 31, d0 >> 4, (d0 >> 3) & 1, 0, 0);
                    short8v bh = *(const short8v*)&bfr[bb];
                    short8v bl = *(const short8v*)&bfr[bb + 512];
#pragma unroll
                    for (int j2 = 0; j2 < 8; ++j2) {
                        double xv = (double)(bf2f((ushort)xh[j2]) + bf2f((ushort)xl[j2]));
                        double bv = (double)(bf2f((ushort)bh[j2]) + bf2f((ushort)bl[j2]));
                        smd = fma(xv, bv, smd);
                    }
                }
                float sim  = (float)smd;
                float dist = __fsub_rn(__fadd_rn(f2, c2[pc]), __fmul_rn(2.0f, sim));
                if (dist < best || (dist == best && pc < bi)) { best = dist; bi = pc; }
            }
            kfin[i][r] = bi;
        }
    }
    __syncthreads();

    // ---- rare fallback: full np-mimic scan (one wave per overflowed pair) ----
    for (int t = wv; t < rep_cnt; t += 4) {
        int e = rep_list[t];
        int i = e >> 6, r = e & 63;
        const float* dic; int K, base;
        if      (i == 0) { dic = dc0; K = 64;  base = 0;   }
        else if (i == 1) { dic = dc1; K = 128; base = 64;  }
        else if (i == 2) { dic = dc2; K = 256; base = 192; }
        else             { dic = dc3; K = 512; base = 448; }
        const float* xrow = x + (rowbase + r) * D;
        const float f2 = f2row[r];
        float bestv = FLT_MAX; int besti = 0x7fffffff;
        for (int c = lane; c < K; c += 64) {
            float  cn  = 0.0f;
            double smd = 0.0;
            for (int d = 0; d < D; ++d) {
                float bv = dic[d * K + c];
                cn  = __fadd_rn(cn, __fmul_rn(bv, bv));
                smd = fma((double)xrow[d], (double)bv, smd);
            }
            float sim  = (float)smd;
            float dist = __fsub_rn(__fadd_rn(f2, cn), __fmul_rn(2.0f, sim));
            if (dist < bestv) { bestv = dist; besti = c; }
        }
#pragma unroll
        for (int off = 32; off; off >>= 1) {
            float ov = __shfl_xor(bestv, off);
            int   oi = __shfl_xor(besti, off);
            if (ov < bestv || (ov == bestv && oi < besti)) { bestv = ov; besti = oi; }
        }
        if (lane == 0) kfin[i][r] = base + besti;
    }
    __syncthreads();

    // ---- epilogue: x from LDS hi/lo, q gathered hi+lo, fp64 loss ----
    const float a0 = ws[0], a1 = ws[1], a2 = ws[2], a3 = ws[3];
    double l0 = 0.0, l1 = 0.0, l2 = 0.0, l3 = 0.0;
    {
        for (int r = 0; r < RPB; ++r) {
            const int bu = aidx(r, tid);
            const float xv = bf2f(afrag[bu]) + bf2f(afrag[bu + ASTRIDE]);
            const int i0 = kfin[0][r], i1 = kfin[1][r], i2 = kfin[2][r], i3 = kfin[3][r];
            const float q0 = dget(bfr, i0, tid);
            const float q1 = dget(bfr, i1, tid);
            const float q2 = dget(bfr, i2, tid);
            const float q3 = dget(bfr, i3, tid);
            float wq = __fadd_rn(__fadd_rn(__fadd_rn(__fmul_rn(a0, q0), __fmul_rn(a1, q1)),
                                           __fmul_rn(a2, q2)), __fmul_rn(a3, q3));
            out[(rowbase + r) * D + tid] = __fadd_rn(xv, __fsub_rn(wq, xv));
            const float e0 = xv - q0, e1 = xv - q1, e2 = xv - q2, e3 = xv - q3;
            l0 = fma((double)e0, (double)e0, l0);
            l1 = fma((double)e1, (double)e1, l1);
            l2 = fma((double)e2, (double)e2, l2);
            l3 = fma((double)e3, (double)e3, l3);
        }
    }
#pragma unroll
    for (int off = 32; off; off >>= 1) {
        l0 += __shfl_down(l0, off); l1 += __shfl_down(l1, off);
        l2 += __shfl_down(l2, off); l3 += __shfl_down(l3, off);
    }
    if (lane == 0) { lred[wv][0] = l0; lred[wv][1] = l1; lred[wv][2] = l2; lred[wv][3] = l3; }
    __syncthreads();
    if (tid == 0) {
        double* lacc = (double*)(ws + 968);
#pragma unroll
        for (int i = 0; i < 4; ++i)
            atomicAdd(lacc + i, lred[0][i] + lred[1][i] + lred[2][i] + lred[3][i]);
    }
}

__global__ void vq_fin(const float* __restrict__ ws, float* __restrict__ out)
{
    if (threadIdx.x == 0) {
        const double* lacc = (const double*)(ws + 968);
        const double* dal  = (const double*)(ws + 976);
        double s = 0.0;
#pragma unroll
        for (int i = 0; i < 4; ++i) s += (lacc[i] * (1.0 / 16777216.0)) * dal[i];
        out[16777216] = (float)(s + 0.25 * s);
    }
}

extern "C" void kernel_launch(void* const* d_in, const int* in_sizes, int n_in,
                              void* d_out, int out_size, void* d_ws, size_t ws_size,
                              hipStream_t stream)
{
    const float* x   = (const float*)d_in[0];
    const float* av  = (const float*)d_in[1];
    const float* dc0 = (const float*)d_in[2];
    const float* dc1 = (const float*)d_in[3];
    const float* dc2 = (const float*)d_in[4];
    const float* dc3 = (const float*)d_in[5];
    float* out = (float*)d_out;
    float* ws  = (float*)d_ws;

    hipLaunchKernelGGL(vq_prep, dim3(30), dim3(256), 0, stream, av, dc0, dc1, dc2, dc3, ws);
    hipLaunchKernelGGL(vq_main, dim3(NROWS / RPB), dim3(256), 0, stream,
                       x, dc0, dc1, dc2, dc3, ws, out);
    hipLaunchKernelGGL(vq_fin, dim3(1), dim3(64), 0, stream, ws, out);
}

// Round 7
// 260.156 us; speedup vs baseline: 3.2223x; 1.5515x over previous
//
#include <hip/hip_runtime.h>
#include <float.h>
#include <math.h>

#define D 256
#define NROWS 65536
#define RPB 64
#define EPS_CAND 0.02f   // hi-only score error 13-sigma (1.5e-3) + np quantization; candidates ~1.1/row
#define CAP 6            // max candidates per (dict,row); overflow -> full np-mimic fallback
#define WSFRAG 1024
#define ASTRIDE 520      // ushorts per (rt,s,p) LDS fragment block: 512 + 8 pad

// ws float layout:
//  [0..3]     alpha (float)
//  [4..963]   packed col norms ||c||^2, SEQUENTIAL UNFUSED fp32 (= numpy's axis-0 reduce)
//  [968..975] 4 doubles: per-dict loss accumulators
//  [976..983] 4 doubles: alpha fp64
//  [1024..]   dict fragments: ushort[30 tiles][16 ksteps][2 splits][64 lanes][8]

typedef __attribute__((ext_vector_type(8)))  short short8v;
typedef __attribute__((ext_vector_type(16))) float f32x16;
typedef __attribute__((ext_vector_type(4)))  float float4v;
typedef __attribute__((ext_vector_type(4)))  uint  uint4v;

__device__ __forceinline__ ushort f2bf(float v) {
    uint u = __float_as_uint(v);
    u += 0x7fffu + ((u >> 16) & 1u);
    return (ushort)(u >> 16);
}
__device__ __forceinline__ float bf2f(ushort u) { return __uint_as_float(((uint)u) << 16); }

__device__ __forceinline__ int fidx(int ct, int c, int s, int half, int j, int p) {
    return ((ct * 16 + s) * 2 + p) * 512 + (c + 32 * half) * 8 + j;   // ws (global) layout
}
__device__ __forceinline__ float dget(const ushort* fr, int pc, int d) {
    int b = fidx(pc >> 5, pc & 31, d >> 4, (d >> 3) & 1, d & 7, 0);
    return bf2f(fr[b]) + bf2f(fr[b + 512]);
}
// afrag (LDS) index of x[row][d], hi plane (lo at +ASTRIDE)
__device__ __forceinline__ int aidx(int row, int d) {
    return (((row >> 5) * 16 + (d >> 4)) * 2) * ASTRIDE + ((row & 31) + 32 * ((d >> 3) & 1)) * 8 + (d & 7);
}
__device__ __forceinline__ void dic_sel(int pc, const float* dc0, const float* dc1,
                                        const float* dc2, const float* dc3,
                                        const float*& dic, int& K, int& kk) {
    if      (pc < 64)  { dic = dc0; K = 64;  kk = pc;       }
    else if (pc < 192) { dic = dc1; K = 128; kk = pc - 64;  }
    else if (pc < 448) { dic = dc2; K = 256; kk = pc - 192; }
    else               { dic = dc3; K = 512; kk = pc - 448; }
}

__global__ void vq_prep(const float* __restrict__ av,
                        const float* __restrict__ dc0, const float* __restrict__ dc1,
                        const float* __restrict__ dc2, const float* __restrict__ dc3,
                        float* __restrict__ ws)
{
    int t = blockIdx.x * 256 + threadIdx.x;
    ushort* fr = (ushort*)(ws + WSFRAG);
    if (t == 0) {
        double x0 = av[0], x1 = av[1], x2 = av[2], x3 = av[3];
        double m = fmax(fmax(x0, x1), fmax(x2, x3));
        double e0 = exp(x0 - m), e1 = exp(x1 - m), e2 = exp(x2 - m), e3 = exp(x3 - m);
        double inv = 1.0 / (e0 + e1 + e2 + e3);
        ws[0] = (float)(e0 * inv); ws[1] = (float)(e1 * inv);
        ws[2] = (float)(e2 * inv); ws[3] = (float)(e3 * inv);
        double* lacc = (double*)(ws + 968);
        lacc[0] = 0.0; lacc[1] = 0.0; lacc[2] = 0.0; lacc[3] = 0.0;
        double* dal = (double*)(ws + 976);
        dal[0] = e0 * inv; dal[1] = e1 * inv; dal[2] = e2 * inv; dal[3] = e3 * inv;
    }
    if (t < 960) {   // np-exact column norms: sequential unfused fp32 (numpy axis-0 reduce)
        const float* dic; int K, kk;
        dic_sel(t, dc0, dc1, dc2, dc3, dic, K, kk);
        float s = 0.0f;
        for (int d = 0; d < D; ++d) { float v = dic[d * K + kk]; s = __fadd_rn(s, __fmul_rn(v, v)); }
        ws[4 + t] = s;
    }
    if (t < 7680) {
        int pc = t >> 3;
        const float* dic; int K, kk;
        dic_sel(pc, dc0, dc1, dc2, dc3, dic, K, kk);
        int ct = pc >> 5, c = pc & 31;
        int kb = (t & 7) * 32;
        for (int k = kb; k < kb + 32; ++k) {
            float v = dic[k * K + kk];
            ushort hu = f2bf(v);
            ushort lu = f2bf(v - bf2f(hu));
            fr[fidx(ct, c, k >> 4, (k >> 3) & 1, k & 7, 0)] = hu;
            fr[fidx(ct, c, k >> 4, (k >> 3) & 1, k & 7, 1)] = lu;
        }
    }
}

// hi-plane-only loads (p=0)
__device__ __forceinline__ void load_Bh(short8v (&B)[2], const ushort* bfr, int ct0, int s, int lane) {
#pragma unroll
    for (int cc = 0; cc < 2; ++cc)
        B[cc] = *(const short8v*)&bfr[(((ct0 + cc) * 16 + s) * 2) * 512 + lane * 8];
}
__device__ __forceinline__ void load_Ah(short8v (&A)[2], const ushort* af, int s, int lane) {
#pragma unroll
    for (int rt = 0; rt < 2; ++rt)
        A[rt] = *(const short8v*)&af[((rt * 16 + s) * 2) * ASTRIDE + lane * 8];
}

// One 2-col-tile group, hi-only scoring: 4 MFMA per kstep. emit(rt,reg,scA,scB).
// MFMA order fixed by the acc dependence chain -> bitwise identical between passes.
template<class F>
__device__ __forceinline__ void gemm_group(const ushort* af, const ushort* bfr,
                                           int ct0, int lane, float c2A, float c2B, F&& emit)
{
    f32x16 acc[2][2];
#pragma unroll
    for (int a = 0; a < 2; ++a)
#pragma unroll
        for (int b = 0; b < 2; ++b) acc[a][b] = (f32x16)(0.0f);

    short8v A[2][2], B[2][2];   // [buf][rt] / [buf][cc]
    load_Ah(A[0], af, 0, lane);
    load_Bh(B[0], bfr, ct0, 0, lane);
#pragma unroll
    for (int s = 0; s < 16; ++s) {
        if (s < 15) {
            load_Ah(A[(s + 1) & 1], af, s + 1, lane);
            load_Bh(B[(s + 1) & 1], bfr, ct0, s + 1, lane);
        }
        const int cur = s & 1;
#pragma unroll
        for (int rt = 0; rt < 2; ++rt)
#pragma unroll
            for (int cc = 0; cc < 2; ++cc)
                acc[rt][cc] = __builtin_amdgcn_mfma_f32_32x32x16_bf16(A[cur][rt], B[cur][cc], acc[rt][cc], 0, 0, 0);
    }
#pragma unroll
    for (int rt = 0; rt < 2; ++rt)
#pragma unroll
        for (int reg = 0; reg < 16; ++reg)
            emit(rt, reg, fmaf(-2.0f, acc[rt][0][reg], c2A), fmaf(-2.0f, acc[rt][1][reg], c2B));
}

__global__ void __launch_bounds__(256, 2) vq_main(
    const float* __restrict__ x,
    const float* __restrict__ dc0, const float* __restrict__ dc1,
    const float* __restrict__ dc2, const float* __restrict__ dc3,
    float* __restrict__ ws, float* __restrict__ out)
{
    __shared__ double lred[4][4];
    __shared__ __align__(16) ushort afrag[64 * ASTRIDE];   // 66560 B
    __shared__ float slotmin[5][64];      // pass-1 per-slot min value
    __shared__ float thrL[4][64];         // min1 + EPS_CAND
    __shared__ float f2row[64];
    __shared__ int   cnt[4][64];
    __shared__ int   cand[4][64][CAP];
    __shared__ int   kfin[4][64];
    __shared__ int   rep_list[64];
    __shared__ int   rep_cnt;

    const int tid  = threadIdx.x;
    const int lane = tid & 63;
    const int wv   = __builtin_amdgcn_readfirstlane(tid >> 6);
    const int lcol = lane & 31, half = lane >> 5;
    const size_t rowbase = (size_t)blockIdx.x * RPB;

    if (tid == 0) rep_cnt = 0;
    for (int i = tid; i < 256; i += 256) { (&cnt[0][0])[i] = 0; }

    // ---- Stage A: x -> bf16 hi/lo fragments (b128 writes) ----
    const float4v* x4 = (const float4v*)(x + rowbase * D);
    for (int it = 0; it < 8; ++it) {
        int f = it * 256 + tid;
        int row = f >> 5, sh = f & 31, s = sh >> 1, hf = sh & 1;
        float4v va = x4[row * 64 + s * 4 + hf * 2];
        float4v vb = x4[row * 64 + s * 4 + hf * 2 + 1];
        ushort h[8], l[8];
#pragma unroll
        for (int i = 0; i < 4; ++i) {
            float u = va[i], w = vb[i];
            h[i]     = f2bf(u); l[i]     = f2bf(u - bf2f(h[i]));
            h[4 + i] = f2bf(w); l[4 + i] = f2bf(w - bf2f(h[4 + i]));
        }
        int bu = (((row >> 5) * 16 + s) * 2) * ASTRIDE + ((row & 31) + 32 * hf) * 8;
        uint4v Hv = { (uint)h[0] | ((uint)h[1] << 16), (uint)h[2] | ((uint)h[3] << 16),
                      (uint)h[4] | ((uint)h[5] << 16), (uint)h[6] | ((uint)h[7] << 16) };
        uint4v Lv = { (uint)l[0] | ((uint)l[1] << 16), (uint)l[2] | ((uint)l[3] << 16),
                      (uint)l[4] | ((uint)l[5] << 16), (uint)l[6] | ((uint)l[7] << 16) };
        *(uint4v*)&afrag[bu]           = Hv;
        *(uint4v*)&afrag[bu + ASTRIDE] = Lv;
    }
    __syncthreads();

    // f2 per row (fp64 exact -> fp32; any fp32 value in the binade is grid-aligned)
    if (tid < 64) {
        double s = 0.0;
        for (int d0 = 0; d0 < D; d0 += 8) {
            int xb = aidx(tid, d0);
            short8v xh = *(const short8v*)&afrag[xb];
            short8v xl = *(const short8v*)&afrag[xb + ASTRIDE];
#pragma unroll
            for (int j = 0; j < 8; ++j) {
                double xv = (double)(bf2f((ushort)xh[j]) + bf2f((ushort)xl[j]));
                s = fma(xv, xv, s);
            }
        }
        f2row[tid] = (float)s;
    }

    const ushort* bfr = (const ushort*)(ws + WSFRAG);
    const float*  c2  = ws + 4;
    const int ngroups = (wv == 0) ? 3 : 4;

    // ---- pass 1: per-(dict,row) min value only ----
    {
        float rv1[2][16];
#pragma unroll
        for (int rt = 0; rt < 2; ++rt)
#pragma unroll
            for (int r = 0; r < 16; ++r) rv1[rt][r] = FLT_MAX;

        for (int g = 0; g < ngroups; ++g) {
            const int ct0 = (wv == 0) ? 2 * g : 6 + (wv - 1) * 8 + 2 * g;
            gemm_group(afrag, bfr, ct0, lane, c2[ct0 * 32 + lcol], c2[ct0 * 32 + 32 + lcol],
                [&](int rt, int reg, float sA, float sB) {
                    rv1[rt][reg] = fminf(rv1[rt][reg], fminf(sA, sB));
                });
            const bool doflush = (wv == 0) ? (g == 0 || g == 2) : (g == 3);
            if (doflush) {
                const int slot = (wv == 0) ? ((g == 0) ? 0 : 1) : wv + 1;
#pragma unroll
                for (int rt = 0; rt < 2; ++rt)
#pragma unroll
                    for (int r = 0; r < 16; ++r) {
                        float v = rv1[rt][r];
#pragma unroll
                        for (int off = 1; off <= 16; off <<= 1) v = fminf(v, __shfl_xor(v, off));
                        if (lcol == r)
                            slotmin[slot][rt * 32 + (r & 3) + 8 * (r >> 2) + 4 * half] = v;
                        rv1[rt][r] = FLT_MAX;
                    }
            }
        }
    }
    __syncthreads();

    // combine slots -> threshold
    {
        int i = tid >> 6, r = tid & 63;
        float m1 = (i < 3) ? slotmin[i][r] : fminf(slotmin[3][r], slotmin[4][r]);
        thrL[i][r] = m1 + EPS_CAND;
    }
    __syncthreads();

    // ---- pass 2: recompute scores (bitwise same), collect candidates ----
    for (int g = 0; g < ngroups; ++g) {
        const int ct0 = (wv == 0) ? 2 * g : 6 + (wv - 1) * 8 + 2 * g;
        const int dct = (wv == 0) ? ((g == 0) ? 0 : 1) : ((wv == 1) ? 2 : 3);
        gemm_group(afrag, bfr, ct0, lane, c2[ct0 * 32 + lcol], c2[ct0 * 32 + 32 + lcol],
            [&](int rt, int reg, float sA, float sB) {
                const int row = rt * 32 + (reg & 3) + 8 * (reg >> 2) + 4 * half;
                const float thr = thrL[dct][row];
                if (sA < thr) {
                    int pos = atomicAdd(&cnt[dct][row], 1);
                    if (pos < CAP) cand[dct][row][pos] = ct0 * 32 + lcol;
                }
                if (sB < thr) {
                    int pos = atomicAdd(&cnt[dct][row], 1);
                    if (pos < CAP) cand[dct][row][pos] = ct0 * 32 + 32 + lcol;
                }
            });
    }
    __syncthreads();

    // ---- final select: np-mimic among candidates (thread = (dict,row)) ----
    {
        const int i = tid >> 6, r = tid & 63;
        const int n = cnt[i][r];
        if (n > CAP) {
            int p = atomicAdd(&rep_cnt, 1);
            rep_list[p] = (i << 6) | r;
        } else {
            const float f2 = f2row[r];
            float best = FLT_MAX; int bi = 0x7fffffff;
            for (int j = 0; j < n; ++j) {
                const int pc = cand[i][r][j];
                double smd = 0.0;
                for (int d0 = 0; d0 < D; d0 += 8) {
                    int xb = aidx(r, d0);
                    short8v xh = *(const short8v*)&afrag[xb];
                    short8v xl = *(const short8v*)&afrag[xb + ASTRIDE];
                    int bb = fidx(pc >> 5, pc & 31, d0 >> 4, (d0 >> 3) & 1, 0, 0);
                    short8v bh = *(const short8v*)&bfr[bb];
                    short8v bl = *(const short8v*)&bfr[bb + 512];
#pragma unroll
                    for (int j2 = 0; j2 < 8; ++j2) {
                        double xv = (double)(bf2f((ushort)xh[j2]) + bf2f((ushort)xl[j2]));
                        double bv = (double)(bf2f((ushort)bh[j2]) + bf2f((ushort)bl[j2]));
                        smd = fma(xv, bv, smd);
                    }
                }
                float sim  = (float)smd;
                float dist = __fsub_rn(__fadd_rn(f2, c2[pc]), __fmul_rn(2.0f, sim));
                if (dist < best || (dist == best && pc < bi)) { best = dist; bi = pc; }
            }
            kfin[i][r] = bi;
        }
    }
    __syncthreads();

    // ---- rare fallback: full np-mimic scan (one wave per overflowed pair) ----
    for (int t = wv; t < rep_cnt; t += 4) {
        int e = rep_list[t];
        int i = e >> 6, r = e & 63;
        const float* dic; int K, base;
        if      (i == 0) { dic = dc0; K = 64;  base = 0;   }
        else if (i == 1) { dic = dc1; K = 128; base = 64;  }
        else if (i == 2) { dic = dc2; K = 256; base = 192; }
        else             { dic = dc3; K = 512; base = 448; }
        const float* xrow = x + (rowbase + r) * D;
        const float f2 = f2row[r];
        float bestv = FLT_MAX; int besti = 0x7fffffff;
        for (int c = lane; c < K; c += 64) {
            float  cn  = 0.0f;
            double smd = 0.0;
            for (int d = 0; d < D; ++d) {
                float bv = dic[d * K + c];
                cn  = __fadd_rn(cn, __fmul_rn(bv, bv));
                smd = fma((double)xrow[d], (double)bv, smd);
            }
            float sim  = (float)smd;
            float dist = __fsub_rn(__fadd_rn(f2, cn), __fmul_rn(2.0f, sim));
            if (dist < bestv) { bestv = dist; besti = c; }
        }
#pragma unroll
        for (int off = 32; off; off >>= 1) {
            float ov = __shfl_xor(bestv, off);
            int   oi = __shfl_xor(besti, off);
            if (ov < bestv || (ov == bestv && oi < besti)) { bestv = ov; besti = oi; }
        }
        if (lane == 0) kfin[i][r] = base + besti;
    }
    __syncthreads();

    // ---- epilogue: x from LDS hi/lo, q gathered hi+lo, fp64 loss ----
    const float a0 = ws[0], a1 = ws[1], a2 = ws[2], a3 = ws[3];
    double l0 = 0.0, l1 = 0.0, l2 = 0.0, l3 = 0.0;
    {
        for (int r = 0; r < RPB; ++r) {
            const int bu = aidx(r, tid);
            const float xv = bf2f(afrag[bu]) + bf2f(afrag[bu + ASTRIDE]);
            const int i0 = kfin[0][r], i1 = kfin[1][r], i2 = kfin[2][r], i3 = kfin[3][r];
            const float q0 = dget(bfr, i0, tid);
            const float q1 = dget(bfr, i1, tid);
            const float q2 = dget(bfr, i2, tid);
            const float q3 = dget(bfr, i3, tid);
            float wq = __fadd_rn(__fadd_rn(__fadd_rn(__fmul_rn(a0, q0), __fmul_rn(a1, q1)),
                                           __fmul_rn(a2, q2)), __fmul_rn(a3, q3));
            out[(rowbase + r) * D + tid] = __fadd_rn(xv, __fsub_rn(wq, xv));
            const float e0 = xv - q0, e1 = xv - q1, e2 = xv - q2, e3 = xv - q3;
            l0 = fma((double)e0, (double)e0, l0);
            l1 = fma((double)e1, (double)e1, l1);
            l2 = fma((double)e2, (double)e2, l2);
            l3 = fma((double)e3, (double)e3, l3);
        }
    }
#pragma unroll
    for (int off = 32; off; off >>= 1) {
        l0 += __shfl_down(l0, off); l1 += __shfl_down(l1, off);
        l2 += __shfl_down(l2, off); l3 += __shfl_down(l3, off);
    }
    if (lane == 0) { lred[wv][0] = l0; lred[wv][1] = l1; lred[wv][2] = l2; lred[wv][3] = l3; }
    __syncthreads();
    if (tid == 0) {
        double* lacc = (double*)(ws + 968);
#pragma unroll
        for (int i = 0; i < 4; ++i)
            atomicAdd(lacc + i, lred[0][i] + lred[1][i] + lred[2][i] + lred[3][i]);
    }
}

__global__ void vq_fin(const float* __restrict__ ws, float* __restrict__ out)
{
    if (threadIdx.x == 0) {
        const double* lacc = (const double*)(ws + 968);
        const double* dal  = (const double*)(ws + 976);
        double s = 0.0;
#pragma unroll
        for (int i = 0; i < 4; ++i) s += (lacc[i] * (1.0 / 16777216.0)) * dal[i];
        out[16777216] = (float)(s + 0.25 * s);
    }
}

extern "C" void kernel_launch(void* const* d_in, const int* in_sizes, int n_in,
                              void* d_out, int out_size, void* d_ws, size_t ws_size,
                              hipStream_t stream)
{
    const float* x   = (const float*)d_in[0];
    const float* av  = (const float*)d_in[1];
    const float* dc0 = (const float*)d_in[2];
    const float* dc1 = (const float*)d_in[3];
    const float* dc2 = (const float*)d_in[4];
    const float* dc3 = (const float*)d_in[5];
    float* out = (float*)d_out;
    float* ws  = (float*)d_ws;

    hipLaunchKernelGGL(vq_prep, dim3(30), dim3(256), 0, stream, av, dc0, dc1, dc2, dc3, ws);
    hipLaunchKernelGGL(vq_main, dim3(NROWS / RPB), dim3(256), 0, stream,
                       x, dc0, dc1, dc2, dc3, ws, out);
    hipLaunchKernelGGL(vq_fin, dim3(1), dim3(64), 0, stream, ws, out);
}